// Round 7
// baseline (214.995 us; speedup 1.0000x reference)
//
#include <hip/hip_runtime.h>

// GCN, algebraically collapsed + two-sided 128-node bucket partition.
//   y[n]  = dinv[n]*x[n]            (stored fp16x8 = 16B -> ONE gather op/edge)
//   a[d]  = dinv[d]*(sum_{s->d} y[s] + y[d])
//   h1[d] = relu(a[d] @ W1 + b1)
//   c[d]  = dinv[d]*sdeg[d] + dinv[d]^2,  sdeg[s] = sum_{d: s->d} dinv[d]
//   v     = sum_d c[d]*h1[d];  g = (1/N)*v@W2 + b2
//   out   = concat(g, relu(state@Wm+bm)) @ Wc + bc
// R7: measured invariant across R4-R6 = ~25-30ns per divergent global memory
// op (read/write/atomic alike), insensitive to occupancy/batching/NT. So:
// (a) fp16-pack y -> dst-side gather 2 ops -> 1 op per edge;
// (b) NPB 256->128, PCH 4096->2048 -> ~3 blocks/CU (was ~1.5, tail-bound);
// (c) revert NT on bufD/bufS (may have forced HBM round-trips, R5->R6 regr).

#define NPB   128      // nodes per bucket
#define CAP   2048     // edge capacity per bucket (mean 1600, +11 sigma)
#define MAXB  1024     // max buckets (N <= 131072)
#define PCH   2048     // edges per partition block
#define PTH   512      // partition block threads
#define PK    (PCH/PTH) // 4 edges per thread

typedef unsigned uv4 __attribute__((ext_vector_type(4)));
typedef _Float16 half8 __attribute__((ext_vector_type(8)));

// Block-level radix scatter: rank via LDS atomics, exclusive-scan, stage
// bucket-ordered in LDS, write contiguous runs.
// Payload u32: low 17 bits = other-endpoint id, bits [23:17] = own low-7.
__launch_bounds__(PTH)
__global__ void k_part(const int* __restrict__ src, const int* __restrict__ dst,
                       int E, int nbuck,
                       unsigned* __restrict__ curD, unsigned* __restrict__ curS,
                       unsigned* __restrict__ bufD, unsigned* __restrict__ bufS) {
    __shared__ unsigned       stage[PCH];   //  8 KB
    __shared__ unsigned short bkt[PCH];     //  4 KB
    __shared__ unsigned lc[MAXB], lofs[MAXB], gb[MAXB], sc[MAXB]; // 16 KB
    int t = threadIdx.x;
    int base = blockIdx.x * PCH;
    int cnt = min(PCH, E - base);

    unsigned ss[PK], dd[PK];
#pragma unroll
    for (int k = 0; k < PK; ++k) {
        int e = base + k * PTH + t;
        if (e < E) {
            ss[k] = (unsigned)__builtin_nontemporal_load(src + e);
            dd[k] = (unsigned)__builtin_nontemporal_load(dst + e);
        } else ss[k] = 0xffffffffu;
    }

    for (int side = 0; side < 2; ++side) {
        lc[t] = 0; lc[t + PTH] = 0;
        __syncthreads();

        unsigned br[PK];
#pragma unroll
        for (int k = 0; k < PK; ++k) {
            if (ss[k] == 0xffffffffu) { br[k] = 0xffffffffu; continue; }
            unsigned key = side ? ss[k] : dd[k];
            unsigned b = key >> 7;
            unsigned r = atomicAdd(&lc[b], 1u);
            br[k] = (b << 16) | r;
        }
        __syncthreads();

        // exclusive scan over MAXB entries, 2 per thread (Hillis-Steele)
        unsigned v0 = lc[t], v1 = lc[t + PTH];
        sc[t] = v0; sc[t + PTH] = v1;
        __syncthreads();
        for (int o = 1; o < MAXB; o <<= 1) {
            unsigned a0 = (t >= o) ? sc[t - o] : 0u;
            unsigned a1 = (t + PTH >= o) ? sc[t + PTH - o] : 0u;
            __syncthreads();
            sc[t] += a0; sc[t + PTH] += a1;
            __syncthreads();
        }
        lofs[t] = sc[t] - v0;
        lofs[t + PTH] = sc[t + PTH] - v1;
        unsigned* cur = side ? curS : curD;
        gb[t] = v0 ? atomicAdd(&cur[t], v0) : 0u;
        gb[t + PTH] = v1 ? atomicAdd(&cur[t + PTH], v1) : 0u;
        __syncthreads();

        // stage bucket-ordered
#pragma unroll
        for (int k = 0; k < PK; ++k) {
            if (br[k] == 0xffffffffu) continue;
            unsigned b = br[k] >> 16, r = br[k] & 0xffffu;
            unsigned pos = lofs[b] + r;
            stage[pos] = side ? (dd[k] | ((ss[k] & 127u) << 17))
                              : (ss[k] | ((dd[k] & 127u) << 17));
            bkt[pos] = (unsigned short)b;
        }
        __syncthreads();

        // contiguous-run writeout (plain stores: let L2 keep them warm)
        unsigned* obuf = side ? bufS : bufD;
        for (int i = t; i < cnt; i += PTH) {
            unsigned b = bkt[i];
            obuf[(size_t)b * CAP + gb[b] + ((unsigned)i - lofs[b])] = stage[i];
        }
        __syncthreads();
    }
}

// Per dst-bucket: in-degree via LDS atomics -> dinv, y = fp16(dinv*x).
__launch_bounds__(512)
__global__ void k_prep(const unsigned* __restrict__ bufD, const unsigned* __restrict__ cntD,
                       const float* __restrict__ x, int N,
                       float* __restrict__ dinv, half8* __restrict__ yh) {
    __shared__ unsigned degl[NPB];
    int t = threadIdx.x, b = blockIdx.x;
    if (t < NPB) degl[t] = 0u;
    __syncthreads();
    unsigned cnt = cntD[b];
    unsigned base = (unsigned)t * 4u;
    if (base < cnt) {
        uv4 w = ((const uv4*)(bufD + (size_t)b * CAP))[t];
        unsigned nv = min(cnt - base, 4u);
#pragma unroll
        for (unsigned k = 0; k < 4; ++k)
            if (k < nv) atomicAdd(&degl[w[k] >> 17], 1u);
    }
    __syncthreads();
    if (t < NPB) {
        int n = b * NPB + t;
        if (n < N) {
            float di = rsqrtf((float)(degl[t] + 1u));
            dinv[n] = di;
            float4 u0 = ((const float4*)(x + (size_t)n * 8))[0];
            float4 u1 = ((const float4*)(x + (size_t)n * 8))[1];
            half8 h;
            h[0] = (_Float16)(di * u0.x); h[1] = (_Float16)(di * u0.y);
            h[2] = (_Float16)(di * u0.z); h[3] = (_Float16)(di * u0.w);
            h[4] = (_Float16)(di * u1.x); h[5] = (_Float16)(di * u1.y);
            h[6] = (_Float16)(di * u1.z); h[7] = (_Float16)(di * u1.w);
            yh[n] = h;
        }
    }
}

// Per bucket b: sl = sdeg (dinv gathers over bufS, 1 op/edge); acc = sum of
// in-edge y (fp16 gathers over bufD, 1 op/edge); fused node math + butterfly
// reduce-scatter; fold into global vsum[64].
__launch_bounds__(512)
__global__ void k_sacc(const unsigned* __restrict__ bufD, const unsigned* __restrict__ cntD,
                       const unsigned* __restrict__ bufS, const unsigned* __restrict__ cntS,
                       const half8* __restrict__ yh, const float* __restrict__ dinv,
                       const float* __restrict__ W1, const float* __restrict__ b1,
                       float* __restrict__ vsum, int N) {
    __shared__ float acc[NPB][9];   // +1 pad: spread across banks
    __shared__ float sl[NPB];
    __shared__ float W1s[512];
    __shared__ float b1s[64];
    __shared__ float red[2][64];
    int t = threadIdx.x, b = blockIdx.x;
    W1s[t] = W1[t];
    if (t < 64) b1s[t] = b1[t];
    if (t < NPB) {
#pragma unroll
        for (int j = 0; j < 9; ++j) acc[t][j] = 0.f;
        sl[t] = 0.f;
    }
    __syncthreads();

    unsigned base = (unsigned)t * 4u;

    // sdeg side: 4 independent dinv gathers
    {
        unsigned cnt = cntS[b];
        if (base < cnt) {
            uv4 w = ((const uv4*)(bufS + (size_t)b * CAP))[t];
            unsigned nv = min(cnt - base, 4u);
            float dv[4];
#pragma unroll
            for (unsigned k = 0; k < 4; ++k)
                dv[k] = (k < nv) ? dinv[w[k] & 0x1ffffu] : 0.f;
#pragma unroll
            for (unsigned k = 0; k < 4; ++k)
                if (k < nv) atomicAdd(&sl[w[k] >> 17], dv[k]);
        }
    }
    // feature side: 4 independent 16B fp16 gathers
    {
        unsigned cnt = cntD[b];
        if (base < cnt) {
            uv4 w = ((const uv4*)(bufD + (size_t)b * CAP))[t];
            unsigned nv = min(cnt - base, 4u);
            half8 g[4];
#pragma unroll
            for (unsigned k = 0; k < 4; ++k)
                if (k < nv) g[k] = yh[w[k] & 0x1ffffu];
#pragma unroll
            for (unsigned k = 0; k < 4; ++k) {
                if (k >= nv) continue;
                unsigned dl = w[k] >> 17;
#pragma unroll
                for (int j = 0; j < 8; ++j)
                    atomicAdd(&acc[dl][j], (float)g[k][j]);
            }
        }
    }
    __syncthreads();

    if (t < NPB) {
        int n = b * NPB + t;
        float a[8] = {0.f, 0.f, 0.f, 0.f, 0.f, 0.f, 0.f, 0.f};
        float c = 0.f;
        if (n < N) {
            float di = dinv[n];
            half8 hs = yh[n];
#pragma unroll
            for (int j = 0; j < 8; ++j) a[j] = di * (acc[t][j] + (float)hs[j]);
            c = fmaf(di, sl[t], di * di);
        }

        float vv[64];
#pragma unroll
        for (int k = 0; k < 64; ++k) {
            float h = b1s[k];
#pragma unroll
            for (int j = 0; j < 8; ++j) h = fmaf(a[j], W1s[j * 64 + k], h);
            vv[k] = c * fmaxf(h, 0.f);
        }

        // Butterfly reduce-scatter (validated R2-R6): lane l ends with
        // wave-sum of component l in vv[0]. NPB=128 -> waves 0,1 only.
        int lane = t & 63;
#pragma unroll
        for (int half = 32; half >= 1; half >>= 1) {
            bool upper = (lane & half) != 0;
#pragma unroll
            for (int i = 0; i < 32; ++i) {
                if (i >= half) break;
                float lo = vv[i];
                float hi = vv[i + half];
                float give = upper ? lo : hi;
                float keep = upper ? hi : lo;
                float recv = __shfl_xor(give, half);
                vv[i] = keep + recv;
            }
        }
        red[t >> 6][lane] = vv[0];
    }
    __syncthreads();
    if (t < 64)
        unsafeAtomicAdd(&vsum[t], red[0][t] + red[1][t]);
}

// Single block, 64 threads: g = (1/N)*vsum@W2+b2, s = relu(state@Wm+bm),
// out = [g,s]@Wc+bc.
__global__ void k_final(const float* __restrict__ vsum,
                        const float* __restrict__ W2, const float* __restrict__ b2,
                        const float* __restrict__ state, const float* __restrict__ Wm,
                        const float* __restrict__ bm, const float* __restrict__ Wc,
                        const float* __restrict__ bc, float* __restrict__ out,
                        float inv_n) {
    __shared__ float v[64];
    __shared__ float gs[128];
    int k = threadIdx.x;   // blockDim = 64

    v[k] = vsum[k];
    __syncthreads();

    float g = 0.f;
    for (int j = 0; j < 64; ++j) g = fmaf(v[j], W2[j * 64 + k], g);
    g = fmaf(g, inv_n, b2[k]);

    float s = bm[k];
    for (int j = 0; j < 8; ++j) s = fmaf(state[j], Wm[j * 64 + k], s);
    s = fmaxf(s, 0.f);

    gs[k] = g;
    gs[64 + k] = s;
    __syncthreads();

    if (k < 2) {
        float o = bc[k];
        for (int j = 0; j < 128; ++j) o = fmaf(gs[j], Wc[j * 2 + k], o);
        out[k] = o;
    }
}

extern "C" void kernel_launch(void* const* d_in, const int* in_sizes, int n_in,
                              void* d_out, int out_size, void* d_ws, size_t ws_size,
                              hipStream_t stream) {
    const float* x     = (const float*)d_in[0];
    const float* state = (const float*)d_in[1];
    const float* W1    = (const float*)d_in[2];
    const float* b1    = (const float*)d_in[3];
    const float* W2    = (const float*)d_in[4];
    const float* b2    = (const float*)d_in[5];
    const float* Wm    = (const float*)d_in[6];
    const float* bm    = (const float*)d_in[7];
    const float* Wc    = (const float*)d_in[8];
    const float* bc    = (const float*)d_in[9];
    const int*   ei    = (const int*)d_in[10];

    const int N = in_sizes[0] / 8;
    const int E = in_sizes[10] / 2;
    const int* src = ei;
    const int* dst = ei + E;
    const int nbuck = (N + NPB - 1) / NPB;   // 782 for N=100000

    char* ws = (char*)d_ws;
    size_t off = 0;
    auto alloc = [&](size_t bytes) -> void* {
        void* p = ws + off;
        off += (bytes + 255) & ~(size_t)255;
        return p;
    };
    // Zeroed region: cursors + vsum (~8.5 KB).
    unsigned* curD = (unsigned*)alloc((size_t)MAXB * 4);
    unsigned* curS = (unsigned*)alloc((size_t)MAXB * 4);
    float*    vsum = (float*)   alloc(64 * 4);
    size_t zero_bytes = off;
    // No-init region.
    unsigned* bufD  = (unsigned*)alloc((size_t)nbuck * CAP * 4);
    unsigned* bufS  = (unsigned*)alloc((size_t)nbuck * CAP * 4);
    float*    dinv  = (float*)   alloc((size_t)N * 4);
    half8*    yh    = (half8*)   alloc((size_t)N * 16);
    (void)ws_size; (void)n_in; (void)out_size;

    hipMemsetAsync(d_ws, 0, zero_bytes, stream);

    k_part<<<(E + PCH - 1) / PCH, PTH, 0, stream>>>(src, dst, E, nbuck,
                                                    curD, curS, bufD, bufS);
    k_prep<<<nbuck, 512, 0, stream>>>(bufD, curD, x, N, dinv, yh);
    k_sacc<<<nbuck, 512, 0, stream>>>(bufD, curD, bufS, curS, yh, dinv,
                                      W1, b1, vsum, N);
    k_final<<<1, 64, 0, stream>>>(vsum, W2, b2, state, Wm, bm, Wc, bc,
                                  (float*)d_out, 1.0f / (float)N);
}

// Round 8
// 160.217 us; speedup vs baseline: 1.3419x; 1.3419x over previous
//
#include <hip/hip_runtime.h>

// GCN, algebraically collapsed + two-sided 128-node bucket partition.
//   y[n]  = dinv[n]*x[n]   (fp16x8, 16B)
//   a[d]  = dinv[d]*(sum_{s->d} y[s] + y[d])
//   h1[d] = relu(a[d] @ W1 + b1)
//   c[d]  = dinv[d]*sdeg[d] + dinv[d]^2,  sdeg[s] = sum_{d: s->d} dinv[d]
//   v     = sum_d c[d]*h1[d];  g = (1/N)*v@W2 + b2
//   out   = concat(g, relu(state@Wm+bm)) @ Wc + bc
// R8: model from R4-R7 = LDS atomic lane-ops dominate (~4cyc each in the
// per-CU LDS RMW pipe; gather width/count and occupancy changes were all
// neutral). k_sacc D-side was 8 atomics/edge -> replace with in-LDS counting
// sort (1 hist atomic/edge, rank = atomic return) + plain place write +
// register-space segmented reduction per node. Zero accumulation atomics.

#define NPB   128      // nodes per bucket
#define CAP   2048     // edge capacity per bucket (mean 1600, +11 sigma)
#define MAXB  1024     // max buckets (N <= 131072)
#define PCH   2048     // edges per partition block
#define PTH   512      // partition block threads
#define PK    (PCH/PTH) // 4 edges per thread

typedef unsigned uv4 __attribute__((ext_vector_type(4)));
typedef _Float16 half8 __attribute__((ext_vector_type(8)));

// Block-level radix scatter (unchanged from R7): rank via LDS atomics,
// exclusive-scan, stage bucket-ordered in LDS, write contiguous runs.
// Payload u32: low 17 bits = other-endpoint id, bits [23:17] = own low-7.
__launch_bounds__(PTH)
__global__ void k_part(const int* __restrict__ src, const int* __restrict__ dst,
                       int E, int nbuck,
                       unsigned* __restrict__ curD, unsigned* __restrict__ curS,
                       unsigned* __restrict__ bufD, unsigned* __restrict__ bufS) {
    __shared__ unsigned       stage[PCH];   //  8 KB
    __shared__ unsigned short bkt[PCH];     //  4 KB
    __shared__ unsigned lc[MAXB], lofs[MAXB], gb[MAXB], sc[MAXB]; // 16 KB
    int t = threadIdx.x;
    int base = blockIdx.x * PCH;
    int cnt = min(PCH, E - base);

    unsigned ss[PK], dd[PK];
#pragma unroll
    for (int k = 0; k < PK; ++k) {
        int e = base + k * PTH + t;
        if (e < E) {
            ss[k] = (unsigned)src[e];
            dd[k] = (unsigned)dst[e];
        } else ss[k] = 0xffffffffu;
    }

    for (int side = 0; side < 2; ++side) {
        lc[t] = 0; lc[t + PTH] = 0;
        __syncthreads();

        unsigned br[PK];
#pragma unroll
        for (int k = 0; k < PK; ++k) {
            if (ss[k] == 0xffffffffu) { br[k] = 0xffffffffu; continue; }
            unsigned key = side ? ss[k] : dd[k];
            unsigned b = key >> 7;
            unsigned r = atomicAdd(&lc[b], 1u);
            br[k] = (b << 16) | r;
        }
        __syncthreads();

        // exclusive scan over MAXB entries, 2 per thread (Hillis-Steele)
        unsigned v0 = lc[t], v1 = lc[t + PTH];
        sc[t] = v0; sc[t + PTH] = v1;
        __syncthreads();
        for (int o = 1; o < MAXB; o <<= 1) {
            unsigned a0 = (t >= o) ? sc[t - o] : 0u;
            unsigned a1 = (t + PTH >= o) ? sc[t + PTH - o] : 0u;
            __syncthreads();
            sc[t] += a0; sc[t + PTH] += a1;
            __syncthreads();
        }
        lofs[t] = sc[t] - v0;
        lofs[t + PTH] = sc[t + PTH] - v1;
        unsigned* cur = side ? curS : curD;
        gb[t] = v0 ? atomicAdd(&cur[t], v0) : 0u;
        gb[t + PTH] = v1 ? atomicAdd(&cur[t + PTH], v1) : 0u;
        __syncthreads();

        // stage bucket-ordered
#pragma unroll
        for (int k = 0; k < PK; ++k) {
            if (br[k] == 0xffffffffu) continue;
            unsigned b = br[k] >> 16, r = br[k] & 0xffffu;
            unsigned pos = lofs[b] + r;
            stage[pos] = side ? (dd[k] | ((ss[k] & 127u) << 17))
                              : (ss[k] | ((dd[k] & 127u) << 17));
            bkt[pos] = (unsigned short)b;
        }
        __syncthreads();

        // contiguous-run writeout
        unsigned* obuf = side ? bufS : bufD;
        for (int i = t; i < cnt; i += PTH) {
            unsigned b = bkt[i];
            obuf[(size_t)b * CAP + gb[b] + ((unsigned)i - lofs[b])] = stage[i];
        }
        __syncthreads();
    }
}

// Per dst-bucket: in-degree via LDS hist (1 atomic/edge) -> dinv, yh.
__launch_bounds__(128)
__global__ void k_prep(const unsigned* __restrict__ bufD, const unsigned* __restrict__ cntD,
                       const float* __restrict__ x, int N,
                       float* __restrict__ dinv, half8* __restrict__ yh) {
    __shared__ unsigned degl[NPB];
    int t = threadIdx.x, b = blockIdx.x;
    degl[t] = 0u;
    __syncthreads();
    unsigned cnt = cntD[b];
    const uv4* eb = (const uv4*)(bufD + (size_t)b * CAP);
#pragma unroll
    for (int r = 0; r < 4; ++r) {
        unsigned base = ((unsigned)t + (unsigned)r * 128u) * 4u;
        if (base < cnt) {
            uv4 w = eb[t + r * 128];
            unsigned nv = min(cnt - base, 4u);
#pragma unroll
            for (unsigned k = 0; k < 4; ++k)
                if (k < nv) atomicAdd(&degl[w[k] >> 17], 1u);
        }
    }
    __syncthreads();
    int n = b * NPB + t;
    if (n < N) {
        float di = rsqrtf((float)(degl[t] + 1u));
        dinv[n] = di;
        float4 u0 = ((const float4*)(x + (size_t)n * 8))[0];
        float4 u1 = ((const float4*)(x + (size_t)n * 8))[1];
        half8 h;
        h[0] = (_Float16)(di * u0.x); h[1] = (_Float16)(di * u0.y);
        h[2] = (_Float16)(di * u0.z); h[3] = (_Float16)(di * u0.w);
        h[4] = (_Float16)(di * u1.x); h[5] = (_Float16)(di * u1.y);
        h[6] = (_Float16)(di * u1.z); h[7] = (_Float16)(di * u1.w);
        yh[n] = h;
    }
}

// Per bucket b:
//   sl[t] = sdeg (LDS float atomic, 1/edge, over bufS)
//   D side: counting-sort bufD by local dst (1 hist atomic/edge; rank =
//   atomic return; plain LDS place), then thread t reduces node t's
//   contiguous run in REGISTERS (no accumulation atomics), fused node math,
//   butterfly reduce-scatter, fold into vsum[64].
__launch_bounds__(128)
__global__ void k_sacc(const unsigned* __restrict__ bufD, const unsigned* __restrict__ cntD,
                       const unsigned* __restrict__ bufS, const unsigned* __restrict__ cntS,
                       const half8* __restrict__ yh, const float* __restrict__ dinv,
                       const float* __restrict__ W1, const float* __restrict__ b1,
                       float* __restrict__ vsum, int N) {
    __shared__ unsigned sorted[CAP];    // 8 KB
    __shared__ unsigned hist[NPB], sc[NPB], eoffs[NPB];
    __shared__ float sl[NPB];
    __shared__ float W1s[512];
    __shared__ float b1s[64];
    __shared__ float red[2][64];
    int t = threadIdx.x, b = blockIdx.x;
#pragma unroll
    for (int r = 0; r < 4; ++r) W1s[t + r * 128] = W1[t + r * 128];
    if (t < 64) b1s[t] = b1[t];
    hist[t] = 0u;
    sl[t] = 0.f;
    __syncthreads();

    // S side: sdeg
    {
        unsigned cnt = cntS[b];
        const uv4* eb = (const uv4*)(bufS + (size_t)b * CAP);
#pragma unroll
        for (int r = 0; r < 4; ++r) {
            unsigned base = ((unsigned)t + (unsigned)r * 128u) * 4u;
            if (base < cnt) {
                uv4 w = eb[t + r * 128];
                unsigned nv = min(cnt - base, 4u);
                float dv[4];
#pragma unroll
                for (unsigned k = 0; k < 4; ++k)
                    dv[k] = (k < nv) ? dinv[w[k] & 0x1ffffu] : 0.f;
#pragma unroll
                for (unsigned k = 0; k < 4; ++k)
                    if (k < nv) atomicAdd(&sl[w[k] >> 17], dv[k]);
            }
        }
    }

    // D side: hist + rank (edge words stay in registers)
    unsigned cnt = cntD[b];
    const uv4* ebD = (const uv4*)(bufD + (size_t)b * CAP);
    uv4 w[4];
    unsigned short rk[16];
#pragma unroll
    for (int r = 0; r < 4; ++r) {
        unsigned base = ((unsigned)t + (unsigned)r * 128u) * 4u;
        if (base < cnt) {
            w[r] = ebD[t + r * 128];
            unsigned nv = min(cnt - base, 4u);
#pragma unroll
            for (unsigned k = 0; k < 4; ++k)
                if (k < nv)
                    rk[r * 4 + k] = (unsigned short)atomicAdd(&hist[w[r][k] >> 17], 1u);
        }
    }
    __syncthreads();

    // exclusive scan of hist (128 bins, 128 threads)
    unsigned hv = hist[t];
    sc[t] = hv;
    __syncthreads();
    for (int o = 1; o < NPB; o <<= 1) {
        unsigned add = (t >= o) ? sc[t - o] : 0u;
        __syncthreads();
        sc[t] += add;
        __syncthreads();
    }
    eoffs[t] = sc[t] - hv;
    __syncthreads();

    // place into sorted order (plain LDS writes)
#pragma unroll
    for (int r = 0; r < 4; ++r) {
        unsigned base = ((unsigned)t + (unsigned)r * 128u) * 4u;
        if (base < cnt) {
            unsigned nv = min(cnt - base, 4u);
#pragma unroll
            for (unsigned k = 0; k < 4; ++k)
                if (k < nv)
                    sorted[eoffs[w[r][k] >> 17] + rk[r * 4 + k]] = w[r][k];
        }
    }
    __syncthreads();

    // segmented gather-reduce: thread t owns local node t (registers only)
    unsigned deg = hist[t], e0 = eoffs[t];
    float a[8] = {0.f, 0.f, 0.f, 0.f, 0.f, 0.f, 0.f, 0.f};
    unsigned i = 0;
    for (; i + 4 <= deg; i += 4) {
        unsigned s0 = sorted[e0 + i]     & 0x1ffffu;
        unsigned s1 = sorted[e0 + i + 1] & 0x1ffffu;
        unsigned s2 = sorted[e0 + i + 2] & 0x1ffffu;
        unsigned s3 = sorted[e0 + i + 3] & 0x1ffffu;
        half8 g0 = yh[s0], g1 = yh[s1], g2 = yh[s2], g3 = yh[s3];
#pragma unroll
        for (int j = 0; j < 8; ++j)
            a[j] += ((float)g0[j] + (float)g1[j]) + ((float)g2[j] + (float)g3[j]);
    }
    for (; i < deg; ++i) {
        half8 g = yh[sorted[e0 + i] & 0x1ffffu];
#pragma unroll
        for (int j = 0; j < 8; ++j) a[j] += (float)g[j];
    }

    int n = b * NPB + t;
    float c = 0.f;
    if (n < N) {
        float di = rsqrtf((float)(deg + 1u));
        half8 hs = yh[n];
#pragma unroll
        for (int j = 0; j < 8; ++j) a[j] = di * (a[j] + (float)hs[j]);
        c = fmaf(di, sl[t], di * di);
    } else {
#pragma unroll
        for (int j = 0; j < 8; ++j) a[j] = 0.f;
    }

    float vv[64];
#pragma unroll
    for (int k = 0; k < 64; ++k) {
        float h = b1s[k];
#pragma unroll
        for (int j = 0; j < 8; ++j) h = fmaf(a[j], W1s[j * 64 + k], h);
        vv[k] = c * fmaxf(h, 0.f);
    }

    // Butterfly reduce-scatter (validated R2-R7): lane l ends with wave-sum
    // of component l in vv[0].
    int lane = t & 63;
#pragma unroll
    for (int half = 32; half >= 1; half >>= 1) {
        bool upper = (lane & half) != 0;
#pragma unroll
        for (int i2 = 0; i2 < 32; ++i2) {
            if (i2 >= half) break;
            float lo = vv[i2];
            float hi = vv[i2 + half];
            float give = upper ? lo : hi;
            float keep = upper ? hi : lo;
            float recv = __shfl_xor(give, half);
            vv[i2] = keep + recv;
        }
    }
    red[t >> 6][lane] = vv[0];
    __syncthreads();
    if (t < 64)
        unsafeAtomicAdd(&vsum[t], red[0][t] + red[1][t]);
}

// Single block, 64 threads: g = (1/N)*vsum@W2+b2, s = relu(state@Wm+bm),
// out = [g,s]@Wc+bc.
__global__ void k_final(const float* __restrict__ vsum,
                        const float* __restrict__ W2, const float* __restrict__ b2,
                        const float* __restrict__ state, const float* __restrict__ Wm,
                        const float* __restrict__ bm, const float* __restrict__ Wc,
                        const float* __restrict__ bc, float* __restrict__ out,
                        float inv_n) {
    __shared__ float v[64];
    __shared__ float gs[128];
    int k = threadIdx.x;   // blockDim = 64

    v[k] = vsum[k];
    __syncthreads();

    float g = 0.f;
    for (int j = 0; j < 64; ++j) g = fmaf(v[j], W2[j * 64 + k], g);
    g = fmaf(g, inv_n, b2[k]);

    float s = bm[k];
    for (int j = 0; j < 8; ++j) s = fmaf(state[j], Wm[j * 64 + k], s);
    s = fmaxf(s, 0.f);

    gs[k] = g;
    gs[64 + k] = s;
    __syncthreads();

    if (k < 2) {
        float o = bc[k];
        for (int j = 0; j < 128; ++j) o = fmaf(gs[j], Wc[j * 2 + k], o);
        out[k] = o;
    }
}

extern "C" void kernel_launch(void* const* d_in, const int* in_sizes, int n_in,
                              void* d_out, int out_size, void* d_ws, size_t ws_size,
                              hipStream_t stream) {
    const float* x     = (const float*)d_in[0];
    const float* state = (const float*)d_in[1];
    const float* W1    = (const float*)d_in[2];
    const float* b1    = (const float*)d_in[3];
    const float* W2    = (const float*)d_in[4];
    const float* b2    = (const float*)d_in[5];
    const float* Wm    = (const float*)d_in[6];
    const float* bm    = (const float*)d_in[7];
    const float* Wc    = (const float*)d_in[8];
    const float* bc    = (const float*)d_in[9];
    const int*   ei    = (const int*)d_in[10];

    const int N = in_sizes[0] / 8;
    const int E = in_sizes[10] / 2;
    const int* src = ei;
    const int* dst = ei + E;
    const int nbuck = (N + NPB - 1) / NPB;   // 782 for N=100000

    char* ws = (char*)d_ws;
    size_t off = 0;
    auto alloc = [&](size_t bytes) -> void* {
        void* p = ws + off;
        off += (bytes + 255) & ~(size_t)255;
        return p;
    };
    // Zeroed region: cursors + vsum.
    unsigned* curD = (unsigned*)alloc((size_t)MAXB * 4);
    unsigned* curS = (unsigned*)alloc((size_t)MAXB * 4);
    float*    vsum = (float*)   alloc(64 * 4);
    size_t zero_bytes = off;
    // No-init region.
    unsigned* bufD  = (unsigned*)alloc((size_t)nbuck * CAP * 4);
    unsigned* bufS  = (unsigned*)alloc((size_t)nbuck * CAP * 4);
    float*    dinv  = (float*)   alloc((size_t)N * 4);
    half8*    yh    = (half8*)   alloc((size_t)N * 16);
    (void)ws_size; (void)n_in; (void)out_size;

    hipMemsetAsync(d_ws, 0, zero_bytes, stream);

    k_part<<<(E + PCH - 1) / PCH, PTH, 0, stream>>>(src, dst, E, nbuck,
                                                    curD, curS, bufD, bufS);
    k_prep<<<nbuck, NPB, 0, stream>>>(bufD, curD, x, N, dinv, yh);
    k_sacc<<<nbuck, NPB, 0, stream>>>(bufD, curD, bufS, curS, yh, dinv,
                                      W1, b1, vsum, N);
    k_final<<<1, 64, 0, stream>>>(vsum, W2, b2, state, Wm, bm, Wc, bc,
                                  (float*)d_out, 1.0f / (float)N);
}

// Round 9
// 134.701 us; speedup vs baseline: 1.5961x; 1.1894x over previous
//
#include <hip/hip_runtime.h>

// GCN, algebraically collapsed + two-sided 256-node bucket partition.
//   y[n]  = dinv[n]*x[n]   (fp16x8, 16B)
//   a[d]  = dinv[d]*(sum_{s->d} y[s] + y[d])
//   h1[d] = relu(a[d] @ W1 + b1)
//   c[d]  = dinv[d]*sdeg[d] + dinv[d]^2,  sdeg[s] = sum_{d: s->d} dinv[d]
//   v     = sum_d c[d]*h1[d];  g = (1/N)*v@W2 + b2
//   out   = concat(g, relu(state@Wm+bm)) @ Wc + bc
// R9: k_part writeout runs were PCH/nbuck = 2 words -> ~32 store transactions
// per wave (R2 disease in disguise). NPB 128->256, PCH 2048->4096 gives runs
// of ~10.5 words (~6 tx/wave, ~5x fewer scatter transactions) while keeping
// 306 part-blocks (>256, per-CU LDS-atomic load stays spread).
// k_sacc keeps R8's counting-sort structure (LDS-atomic model confirmed:
// 8 acc-atomics/edge removed = 98->41.6us) scaled to 256-node buckets.

#define NPB   256      // nodes per bucket
#define CAP   4096     // edge capacity per bucket (mean 3200, +15.8 sigma)
#define MAXB  512      // max buckets (N <= 131072)
#define PCH   4096     // edges per partition block
#define PTH   512      // partition block threads
#define PK    (PCH/PTH) // 8 edges per thread

typedef unsigned uv4 __attribute__((ext_vector_type(4)));
typedef _Float16 half8 __attribute__((ext_vector_type(8)));

// Block-level radix scatter: rank via LDS atomics, exclusive-scan, stage
// bucket-ordered in LDS, write contiguous runs.
// Payload u32: low 17 bits = other-endpoint id, bits [24:17] = own low-8.
__launch_bounds__(PTH)
__global__ void k_part(const int* __restrict__ src, const int* __restrict__ dst,
                       int E, int nbuck,
                       unsigned* __restrict__ curD, unsigned* __restrict__ curS,
                       unsigned* __restrict__ bufD, unsigned* __restrict__ bufS) {
    __shared__ unsigned       stage[PCH];   // 16 KB
    __shared__ unsigned short bkt[PCH];     //  8 KB
    __shared__ unsigned lc[MAXB], lofs[MAXB], gb[MAXB], sc[MAXB]; // 8 KB
    int t = threadIdx.x;
    int base = blockIdx.x * PCH;
    int cnt = min(PCH, E - base);

    unsigned ss[PK], dd[PK];
#pragma unroll
    for (int k = 0; k < PK; ++k) {
        int e = base + k * PTH + t;
        if (e < E) {
            ss[k] = (unsigned)src[e];
            dd[k] = (unsigned)dst[e];
        } else ss[k] = 0xffffffffu;
    }

    for (int side = 0; side < 2; ++side) {
        lc[t] = 0;                       // PTH == MAXB
        __syncthreads();

        unsigned br[PK];
#pragma unroll
        for (int k = 0; k < PK; ++k) {
            if (ss[k] == 0xffffffffu) { br[k] = 0xffffffffu; continue; }
            unsigned key = side ? ss[k] : dd[k];
            unsigned b = key >> 8;
            unsigned r = atomicAdd(&lc[b], 1u);
            br[k] = (b << 16) | r;
        }
        __syncthreads();

        // exclusive scan of lc[0..MAXB), 1 per thread (Hillis-Steele)
        unsigned v = lc[t];
        sc[t] = v;
        __syncthreads();
        for (int o = 1; o < MAXB; o <<= 1) {
            unsigned add = (t >= o) ? sc[t - o] : 0u;
            __syncthreads();
            sc[t] += add;
            __syncthreads();
        }
        lofs[t] = sc[t] - v;
        unsigned* cur = side ? curS : curD;
        gb[t] = v ? atomicAdd(&cur[t], v) : 0u;
        __syncthreads();

        // stage bucket-ordered
#pragma unroll
        for (int k = 0; k < PK; ++k) {
            if (br[k] == 0xffffffffu) continue;
            unsigned b = br[k] >> 16, r = br[k] & 0xffffu;
            unsigned pos = lofs[b] + r;
            stage[pos] = side ? (dd[k] | ((ss[k] & 255u) << 17))
                              : (ss[k] | ((dd[k] & 255u) << 17));
            bkt[pos] = (unsigned short)b;
        }
        __syncthreads();

        // contiguous-run writeout (runs avg ~10.5 words)
        unsigned* obuf = side ? bufS : bufD;
        for (int i = t; i < cnt; i += PTH) {
            unsigned b = bkt[i];
            obuf[(size_t)b * CAP + gb[b] + ((unsigned)i - lofs[b])] = stage[i];
        }
        __syncthreads();
    }
}

// Per dst-bucket: in-degree via LDS hist (1 atomic/edge) -> dinv, yh.
__launch_bounds__(NPB)
__global__ void k_prep(const unsigned* __restrict__ bufD, const unsigned* __restrict__ cntD,
                       const float* __restrict__ x, int N,
                       float* __restrict__ dinv, half8* __restrict__ yh) {
    __shared__ unsigned degl[NPB];
    int t = threadIdx.x, b = blockIdx.x;
    degl[t] = 0u;
    __syncthreads();
    unsigned cnt = cntD[b];
    const uv4* eb = (const uv4*)(bufD + (size_t)b * CAP);
#pragma unroll
    for (int r = 0; r < 4; ++r) {
        unsigned base = ((unsigned)t + (unsigned)r * NPB) * 4u;
        if (base < cnt) {
            uv4 w = eb[t + r * NPB];
            unsigned nv = min(cnt - base, 4u);
#pragma unroll
            for (unsigned k = 0; k < 4; ++k)
                if (k < nv) atomicAdd(&degl[w[k] >> 17], 1u);
        }
    }
    __syncthreads();
    int n = b * NPB + t;
    if (n < N) {
        float di = rsqrtf((float)(degl[t] + 1u));
        dinv[n] = di;
        float4 u0 = ((const float4*)(x + (size_t)n * 8))[0];
        float4 u1 = ((const float4*)(x + (size_t)n * 8))[1];
        half8 h;
        h[0] = (_Float16)(di * u0.x); h[1] = (_Float16)(di * u0.y);
        h[2] = (_Float16)(di * u0.z); h[3] = (_Float16)(di * u0.w);
        h[4] = (_Float16)(di * u1.x); h[5] = (_Float16)(di * u1.y);
        h[6] = (_Float16)(di * u1.z); h[7] = (_Float16)(di * u1.w);
        yh[n] = h;
    }
}

// Per bucket b (R8 structure, NPB=256):
//   sl[t] = sdeg (LDS float atomic, 1/edge, over bufS)
//   D side: counting-sort bufD by local dst (1 hist atomic/edge; rank =
//   atomic return; plain LDS place), thread t reduces node t's contiguous run
//   in registers (no accumulation atomics), fused node math, butterfly
//   reduce-scatter, fold into vsum[64].
__launch_bounds__(NPB)
__global__ void k_sacc(const unsigned* __restrict__ bufD, const unsigned* __restrict__ cntD,
                       const unsigned* __restrict__ bufS, const unsigned* __restrict__ cntS,
                       const half8* __restrict__ yh, const float* __restrict__ dinv,
                       const float* __restrict__ W1, const float* __restrict__ b1,
                       float* __restrict__ vsum, int N) {
    __shared__ unsigned sorted[CAP];    // 16 KB
    __shared__ unsigned hist[NPB], sc[NPB], eoffs[NPB];
    __shared__ float sl[NPB];
    __shared__ float W1s[512];
    __shared__ float b1s[64];
    __shared__ float red[4][64];
    int t = threadIdx.x, b = blockIdx.x;
    W1s[t] = W1[t];
    W1s[t + 256] = W1[t + 256];
    if (t < 64) b1s[t] = b1[t];
    hist[t] = 0u;
    sl[t] = 0.f;
    __syncthreads();

    // S side: sdeg
    {
        unsigned cnt = cntS[b];
        const uv4* eb = (const uv4*)(bufS + (size_t)b * CAP);
#pragma unroll
        for (int r = 0; r < 4; ++r) {
            unsigned base = ((unsigned)t + (unsigned)r * NPB) * 4u;
            if (base < cnt) {
                uv4 w = eb[t + r * NPB];
                unsigned nv = min(cnt - base, 4u);
                float dv[4];
#pragma unroll
                for (unsigned k = 0; k < 4; ++k)
                    dv[k] = (k < nv) ? dinv[w[k] & 0x1ffffu] : 0.f;
#pragma unroll
                for (unsigned k = 0; k < 4; ++k)
                    if (k < nv) atomicAdd(&sl[w[k] >> 17], dv[k]);
            }
        }
    }

    // D side: hist + rank (edge words stay in registers)
    unsigned cnt = cntD[b];
    const uv4* ebD = (const uv4*)(bufD + (size_t)b * CAP);
    uv4 w[4];
    unsigned short rk[16];
#pragma unroll
    for (int r = 0; r < 4; ++r) {
        unsigned base = ((unsigned)t + (unsigned)r * NPB) * 4u;
        if (base < cnt) {
            w[r] = ebD[t + r * NPB];
            unsigned nv = min(cnt - base, 4u);
#pragma unroll
            for (unsigned k = 0; k < 4; ++k)
                if (k < nv)
                    rk[r * 4 + k] = (unsigned short)atomicAdd(&hist[w[r][k] >> 17], 1u);
        }
    }
    __syncthreads();

    // exclusive scan of hist (256 bins, 256 threads)
    unsigned hv = hist[t];
    sc[t] = hv;
    __syncthreads();
    for (int o = 1; o < NPB; o <<= 1) {
        unsigned add = (t >= o) ? sc[t - o] : 0u;
        __syncthreads();
        sc[t] += add;
        __syncthreads();
    }
    eoffs[t] = sc[t] - hv;
    __syncthreads();

    // place into sorted order (plain LDS writes)
#pragma unroll
    for (int r = 0; r < 4; ++r) {
        unsigned base = ((unsigned)t + (unsigned)r * NPB) * 4u;
        if (base < cnt) {
            unsigned nv = min(cnt - base, 4u);
#pragma unroll
            for (unsigned k = 0; k < 4; ++k)
                if (k < nv)
                    sorted[eoffs[w[r][k] >> 17] + rk[r * 4 + k]] = w[r][k];
        }
    }
    __syncthreads();

    // segmented gather-reduce: thread t owns local node t (registers only)
    unsigned deg = hist[t], e0 = eoffs[t];
    float a[8] = {0.f, 0.f, 0.f, 0.f, 0.f, 0.f, 0.f, 0.f};
    unsigned i = 0;
    for (; i + 4 <= deg; i += 4) {
        unsigned s0 = sorted[e0 + i]     & 0x1ffffu;
        unsigned s1 = sorted[e0 + i + 1] & 0x1ffffu;
        unsigned s2 = sorted[e0 + i + 2] & 0x1ffffu;
        unsigned s3 = sorted[e0 + i + 3] & 0x1ffffu;
        half8 g0 = yh[s0], g1 = yh[s1], g2 = yh[s2], g3 = yh[s3];
#pragma unroll
        for (int j = 0; j < 8; ++j)
            a[j] += ((float)g0[j] + (float)g1[j]) + ((float)g2[j] + (float)g3[j]);
    }
    for (; i < deg; ++i) {
        half8 g = yh[sorted[e0 + i] & 0x1ffffu];
#pragma unroll
        for (int j = 0; j < 8; ++j) a[j] += (float)g[j];
    }

    int n = b * NPB + t;
    float c = 0.f;
    if (n < N) {
        float di = rsqrtf((float)(deg + 1u));
        half8 hs = yh[n];
#pragma unroll
        for (int j = 0; j < 8; ++j) a[j] = di * (a[j] + (float)hs[j]);
        c = fmaf(di, sl[t], di * di);
    } else {
#pragma unroll
        for (int j = 0; j < 8; ++j) a[j] = 0.f;
    }

    float vv[64];
#pragma unroll
    for (int k = 0; k < 64; ++k) {
        float h = b1s[k];
#pragma unroll
        for (int j = 0; j < 8; ++j) h = fmaf(a[j], W1s[j * 64 + k], h);
        vv[k] = c * fmaxf(h, 0.f);
    }

    // Butterfly reduce-scatter (validated R2-R8): lane l ends with wave-sum
    // of component l in vv[0].
    int lane = t & 63;
#pragma unroll
    for (int half = 32; half >= 1; half >>= 1) {
        bool upper = (lane & half) != 0;
#pragma unroll
        for (int i2 = 0; i2 < 32; ++i2) {
            if (i2 >= half) break;
            float lo = vv[i2];
            float hi = vv[i2 + half];
            float give = upper ? lo : hi;
            float keep = upper ? hi : lo;
            float recv = __shfl_xor(give, half);
            vv[i2] = keep + recv;
        }
    }
    red[t >> 6][lane] = vv[0];
    __syncthreads();
    if (t < 64)
        unsafeAtomicAdd(&vsum[t], red[0][t] + red[1][t] + red[2][t] + red[3][t]);
}

// Single block, 64 threads: g = (1/N)*vsum@W2+b2, s = relu(state@Wm+bm),
// out = [g,s]@Wc+bc.
__global__ void k_final(const float* __restrict__ vsum,
                        const float* __restrict__ W2, const float* __restrict__ b2,
                        const float* __restrict__ state, const float* __restrict__ Wm,
                        const float* __restrict__ bm, const float* __restrict__ Wc,
                        const float* __restrict__ bc, float* __restrict__ out,
                        float inv_n) {
    __shared__ float v[64];
    __shared__ float gs[128];
    int k = threadIdx.x;   // blockDim = 64

    v[k] = vsum[k];
    __syncthreads();

    float g = 0.f;
    for (int j = 0; j < 64; ++j) g = fmaf(v[j], W2[j * 64 + k], g);
    g = fmaf(g, inv_n, b2[k]);

    float s = bm[k];
    for (int j = 0; j < 8; ++j) s = fmaf(state[j], Wm[j * 64 + k], s);
    s = fmaxf(s, 0.f);

    gs[k] = g;
    gs[64 + k] = s;
    __syncthreads();

    if (k < 2) {
        float o = bc[k];
        for (int j = 0; j < 128; ++j) o = fmaf(gs[j], Wc[j * 2 + k], o);
        out[k] = o;
    }
}

extern "C" void kernel_launch(void* const* d_in, const int* in_sizes, int n_in,
                              void* d_out, int out_size, void* d_ws, size_t ws_size,
                              hipStream_t stream) {
    const float* x     = (const float*)d_in[0];
    const float* state = (const float*)d_in[1];
    const float* W1    = (const float*)d_in[2];
    const float* b1    = (const float*)d_in[3];
    const float* W2    = (const float*)d_in[4];
    const float* b2    = (const float*)d_in[5];
    const float* Wm    = (const float*)d_in[6];
    const float* bm    = (const float*)d_in[7];
    const float* Wc    = (const float*)d_in[8];
    const float* bc    = (const float*)d_in[9];
    const int*   ei    = (const int*)d_in[10];

    const int N = in_sizes[0] / 8;
    const int E = in_sizes[10] / 2;
    const int* src = ei;
    const int* dst = ei + E;
    const int nbuck = (N + NPB - 1) / NPB;   // 391 for N=100000

    char* ws = (char*)d_ws;
    size_t off = 0;
    auto alloc = [&](size_t bytes) -> void* {
        void* p = ws + off;
        off += (bytes + 255) & ~(size_t)255;
        return p;
    };
    // Zeroed region: cursors + vsum.
    unsigned* curD = (unsigned*)alloc((size_t)MAXB * 4);
    unsigned* curS = (unsigned*)alloc((size_t)MAXB * 4);
    float*    vsum = (float*)   alloc(64 * 4);
    size_t zero_bytes = off;
    // No-init region.
    unsigned* bufD  = (unsigned*)alloc((size_t)nbuck * CAP * 4);
    unsigned* bufS  = (unsigned*)alloc((size_t)nbuck * CAP * 4);
    float*    dinv  = (float*)   alloc((size_t)N * 4);
    half8*    yh    = (half8*)   alloc((size_t)N * 16);
    (void)ws_size; (void)n_in; (void)out_size;

    hipMemsetAsync(d_ws, 0, zero_bytes, stream);

    k_part<<<(E + PCH - 1) / PCH, PTH, 0, stream>>>(src, dst, E, nbuck,
                                                    curD, curS, bufD, bufS);
    k_prep<<<nbuck, NPB, 0, stream>>>(bufD, curD, x, N, dinv, yh);
    k_sacc<<<nbuck, NPB, 0, stream>>>(bufD, curD, bufS, curS, yh, dinv,
                                      W1, b1, vsum, N);
    k_final<<<1, 64, 0, stream>>>(vsum, W2, b2, state, Wm, bm, Wc, bc,
                                  (float*)d_out, 1.0f / (float)N);
}